// Round 20
// baseline (145.244 us; speedup 1.0000x reference)
//
#include <hip/hip_runtime.h>
#include <math.h>

// ---------- types / helpers ----------
typedef __attribute__((ext_vector_type(8))) short short8;
typedef __attribute__((ext_vector_type(4))) float f32x4;

__device__ __forceinline__ unsigned short f2bf(float f) {
  unsigned u = __float_as_uint(f);
  unsigned r = (u + 0x7FFFu + ((u >> 16) & 1u)) >> 16;
  return (unsigned short)r;
}

__device__ __forceinline__ float bf2f(unsigned short u) {
  return __uint_as_float((unsigned)u << 16);
}

__device__ __forceinline__ void gload_lds16(const void* gsrc, void* ldst) {
  __builtin_amdgcn_global_load_lds(
      (__attribute__((address_space(1))) void*)(void*)(size_t)(const char*)gsrc,
      (__attribute__((address_space(3))) void*)ldst, 16, 0, 0);
}

// ========== PREP_A: wtrans (0..63) | zero z_sq/slots (64..127) ==========
__global__ __launch_bounds__(512) void prepA_kernel(
    const float* __restrict__ pre_w, float* __restrict__ wtf,
    float* __restrict__ z_sq, float* __restrict__ slots) {
  __shared__ float tile[64][65];
  const int blk = blockIdx.x;
  const int t = threadIdx.x;
  if (blk < 64) {
    const int bc = blk & 15, bd = blk >> 4;
    const int col = t & 63, rr = t >> 6;
#pragma unroll
    for (int i = 0; i < 8; ++i) {
      int row = rr + i * 8;
      tile[row][col] = pre_w[(size_t)(bd * 64 + row) * 1024 + bc * 64 + col];
    }
    __syncthreads();
#pragma unroll
    for (int i = 0; i < 8; ++i) {
      int row = rr + i * 8;
      wtf[(size_t)(bc * 64 + row) * 256 + bd * 64 + col] = tile[col][row];
    }
  } else {
    int i = (blk - 64) * 512 + t;   // 64 blocks * 512 = 32768
    z_sq[i] = 0.f;
    if (i < 2048) slots[i] = 0.f;
  }
}

// ========== PREP_B: pgemm (0..255) | qmat (256..319) | wbv (320) |
//            eproj (321..576) | esq (577..704) | lngelu (705..4800) ==========
__global__ __launch_bounds__(512) void prepB_kernel(
    const float* __restrict__ x, const float* __restrict__ ln_g,
    const float* __restrict__ ln_b, const float* __restrict__ pre_w,
    const float* __restrict__ pre_b, const float* __restrict__ embed,
    const float* __restrict__ post_w, const float* __restrict__ post_b,
    const float* __restrict__ wtf,
    float* __restrict__ g, unsigned short* __restrict__ gbf,
    float* __restrict__ prow, unsigned short* __restrict__ prowbf,
    unsigned short* __restrict__ qbf, float* __restrict__ wbv,
    float* __restrict__ e_sq, float* __restrict__ qv, float* __restrict__ c0,
    float* __restrict__ eproj) {
  __shared__ __align__(16) char smem[49152];
  const int blk = blockIdx.x;
  const int t = threadIdx.x;
  const int sl = t >> 6, jg = t & 63;
  if (blk < 256) {
    // ---- pgemm: P[k][d] = embed[k,:]@wtf[:,d], fp64 accum, 3-round tree ----
    float (*Es)[1024] = (float(*)[1024])smem;             // [4][1024]
    double (*Pd)[1024] = (double(*)[1024])(smem + 16384); // [4][1024]
    const int k0 = blk * 4;
    *(float4*)(&Es[0][0] + t * 8) = *(const float4*)(embed + (size_t)k0 * 1024 + t * 8);
    *(float4*)(&Es[0][0] + t * 8 + 4) = *(const float4*)(embed + (size_t)k0 * 1024 + t * 8 + 4);
    __syncthreads();
    const int cbase = sl * 128;
    double a[4][4] = {};
    const float* wp = wtf + (size_t)cbase * 256 + jg * 4;
#pragma unroll 8
    for (int cc = 0; cc < 128; ++cc) {
      float4 w4 = *(const float4*)(wp + (size_t)cc * 256);
      int c = cbase + cc;
#pragma unroll
      for (int kk = 0; kk < 4; ++kk) {
        double e = (double)Es[kk][c];
        a[kk][0] += (double)w4.x * e;
        a[kk][1] += (double)w4.y * e;
        a[kk][2] += (double)w4.z * e;
        a[kk][3] += (double)w4.w * e;
      }
    }
    if (sl >= 4)
#pragma unroll
      for (int kk = 0; kk < 4; ++kk)
#pragma unroll
        for (int xx = 0; xx < 4; ++xx) Pd[sl - 4][kk * 256 + jg * 4 + xx] = a[kk][xx];
    __syncthreads();
    if (sl < 4)
#pragma unroll
      for (int kk = 0; kk < 4; ++kk)
#pragma unroll
        for (int xx = 0; xx < 4; ++xx) a[kk][xx] += Pd[sl][kk * 256 + jg * 4 + xx];
    __syncthreads();
    if (sl >= 2 && sl < 4)
#pragma unroll
      for (int kk = 0; kk < 4; ++kk)
#pragma unroll
        for (int xx = 0; xx < 4; ++xx) Pd[sl - 2][kk * 256 + jg * 4 + xx] = a[kk][xx];
    __syncthreads();
    if (sl < 2)
#pragma unroll
      for (int kk = 0; kk < 4; ++kk)
#pragma unroll
        for (int xx = 0; xx < 4; ++xx) a[kk][xx] += Pd[sl][kk * 256 + jg * 4 + xx];
    __syncthreads();
    if (sl == 1)
#pragma unroll
      for (int kk = 0; kk < 4; ++kk)
#pragma unroll
        for (int xx = 0; xx < 4; ++xx) Pd[0][kk * 256 + jg * 4 + xx] = a[kk][xx];
    __syncthreads();
    if (sl == 0) {
#pragma unroll
      for (int kk = 0; kk < 4; ++kk) {
        float4 o;
        o.x = (float)(a[kk][0] + Pd[0][kk * 256 + jg * 4 + 0]);
        o.y = (float)(a[kk][1] + Pd[0][kk * 256 + jg * 4 + 1]);
        o.z = (float)(a[kk][2] + Pd[0][kk * 256 + jg * 4 + 2]);
        o.w = (float)(a[kk][3] + Pd[0][kk * 256 + jg * 4 + 3]);
        *(float4*)(prow + (size_t)(k0 + kk) * 256 + jg * 4) = o;
        ushort4 u;
        u.x = f2bf(o.x); u.y = f2bf(o.y); u.z = f2bf(o.z); u.w = f2bf(o.w);
        *(ushort4*)(prowbf + (size_t)(k0 + kk) * 256 + jg * 4) = u;
      }
    }
  } else if (blk < 320) {
    // ---- qmat: Q[a][d] = pre_w[a,:]@wtf[:,d] (bf16) ----
    float (*Es)[1024] = (float(*)[1024])smem;
    float (*Ps)[1024] = (float(*)[1024])(smem + 16384);
    const int a0i = (blk - 256) * 4;
    *(float4*)(&Es[0][0] + t * 8) = *(const float4*)(pre_w + (size_t)a0i * 1024 + t * 8);
    *(float4*)(&Es[0][0] + t * 8 + 4) = *(const float4*)(pre_w + (size_t)a0i * 1024 + t * 8 + 4);
    __syncthreads();
    const int cbase = sl * 128;
    float4 a[4] = {};
    const float* wp = wtf + (size_t)cbase * 256 + jg * 4;
#pragma unroll 8
    for (int cc = 0; cc < 128; ++cc) {
      float4 w4 = *(const float4*)(wp + (size_t)cc * 256);
      int c = cbase + cc;
#pragma unroll
      for (int kk = 0; kk < 4; ++kk) {
        float e = Es[kk][c];
        a[kk].x += w4.x * e; a[kk].y += w4.y * e;
        a[kk].z += w4.z * e; a[kk].w += w4.w * e;
      }
    }
#pragma unroll
    for (int kk = 0; kk < 4; ++kk)
      *(float4*)(&Ps[sl][kk * 256 + jg * 4]) = a[kk];
    __syncthreads();
#pragma unroll
    for (int rep = 0; rep < 2; ++rep) {
      int o = t + rep * 512;
      float s = Ps[0][o] + Ps[1][o] + Ps[2][o] + Ps[3][o] +
                Ps[4][o] + Ps[5][o] + Ps[6][o] + Ps[7][o];
      int kk = o >> 8, j = o & 255;
      qbf[(size_t)(a0i + kk) * 256 + j] = f2bf(s);
    }
  } else if (blk == 320) {
    // ---- wbv = {2*W.b, ||b||^2} ----
    float* Es0 = (float*)smem;
    float (*Ps)[1024] = (float(*)[1024])(smem + 16384);
    const int cbase = sl * 128;
    float4 a = {0.f, 0.f, 0.f, 0.f};
    const float* wp = wtf + (size_t)cbase * 256 + jg * 4;
#pragma unroll 8
    for (int cc = 0; cc < 128; ++cc) {
      float4 w4 = *(const float4*)(wp + (size_t)cc * 256);
      float b = pre_b[cbase + cc];
      a.x += w4.x * b; a.y += w4.y * b; a.z += w4.z * b; a.w += w4.w * b;
    }
    *(float4*)(&Ps[sl][jg * 4]) = a;
    float sb = 0.f;
    if (t < 256) {
      float4 bv = *(const float4*)(pre_b + t * 4);
      sb = bv.x * bv.x + bv.y * bv.y + bv.z * bv.z + bv.w * bv.w;
    }
    for (int m = 32; m; m >>= 1) sb += __shfl_xor(sb, m);
    if ((t & 63) == 0 && t < 256) Es0[t >> 6] = sb;
    __syncthreads();
    if (t < 256) {
      float s = Ps[0][t] + Ps[1][t] + Ps[2][t] + Ps[3][t] +
                Ps[4][t] + Ps[5][t] + Ps[6][t] + Ps[7][t];
      wbv[t] = 2.f * s;
    }
    if (t == 0) wbv[256] = Es0[0] + Es0[1] + Es0[2] + Es0[3];
  } else if (blk < 577) {
    // ---- eproj[k][j] = embed[k,:]@post_w[:,j] + post_b[j] ----
    float (*Es)[1024] = (float(*)[1024])smem;  // [4][1024]
    const int k0 = (blk - 321) * 4;
    *(float4*)(&Es[0][0] + t * 8) = *(const float4*)(embed + (size_t)k0 * 1024 + t * 8);
    *(float4*)(&Es[0][0] + t * 8 + 4) = *(const float4*)(embed + (size_t)k0 * 1024 + t * 8 + 4);
    __syncthreads();
    const int dbase = sl * 128;
    float4 a[4] = {};
    const float* wp = post_w + (size_t)dbase * 256 + jg * 4;
#pragma unroll 8
    for (int dd = 0; dd < 128; ++dd) {
      float4 w4 = *(const float4*)(wp + (size_t)dd * 256);
      int d = dbase + dd;
#pragma unroll
      for (int kk = 0; kk < 4; ++kk) {
        float e = Es[kk][d];
        a[kk].x += w4.x * e; a[kk].y += w4.y * e;
        a[kk].z += w4.z * e; a[kk].w += w4.w * e;
      }
    }
    __syncthreads();               // Es dead; reuse as scratch
    float* scr = (float*)smem;
    if (sl >= 4)
#pragma unroll
      for (int kk = 0; kk < 4; ++kk)
        *(float4*)(scr + (sl - 4) * 1024 + kk * 256 + jg * 4) = a[kk];
    __syncthreads();
    if (sl < 4)
#pragma unroll
      for (int kk = 0; kk < 4; ++kk) {
        float4 v = *(const float4*)(scr + sl * 1024 + kk * 256 + jg * 4);
        a[kk].x += v.x; a[kk].y += v.y; a[kk].z += v.z; a[kk].w += v.w;
      }
    __syncthreads();
    if (sl >= 2 && sl < 4)
#pragma unroll
      for (int kk = 0; kk < 4; ++kk)
        *(float4*)(scr + (sl - 2) * 1024 + kk * 256 + jg * 4) = a[kk];
    __syncthreads();
    if (sl < 2)
#pragma unroll
      for (int kk = 0; kk < 4; ++kk) {
        float4 v = *(const float4*)(scr + sl * 1024 + kk * 256 + jg * 4);
        a[kk].x += v.x; a[kk].y += v.y; a[kk].z += v.z; a[kk].w += v.w;
      }
    __syncthreads();
    if (sl == 1)
#pragma unroll
      for (int kk = 0; kk < 4; ++kk)
        *(float4*)(scr + kk * 256 + jg * 4) = a[kk];
    __syncthreads();
    if (sl == 0) {
      float4 pb = *(const float4*)(post_b + jg * 4);
#pragma unroll
      for (int kk = 0; kk < 4; ++kk) {
        float4 v = *(const float4*)(scr + kk * 256 + jg * 4);
        float4 o;
        o.x = a[kk].x + v.x + pb.x;
        o.y = a[kk].y + v.y + pb.y;
        o.z = a[kk].z + v.z + pb.z;
        o.w = a[kk].w + v.w + pb.w;
        *(float4*)(eproj + (size_t)(k0 + kk) * 256 + jg * 4) = o;
      }
    }
  } else if (blk < 705) {
    // ---- esq: e_sq/qv/c0, 8 k-rows per block ----
    const int l = t & 63, w = t >> 6;
    const int k = (blk - 577) * 8 + w;
    const float* er = embed + (size_t)k * 1024;
    float s1 = 0.f, s2 = 0.f;
#pragma unroll
    for (int j = 0; j < 16; ++j) {
      float e = er[l + 64 * j];
      s1 += e * e;
      s2 += pre_b[l + 64 * j] * e;
    }
    for (int m = 32; m; m >>= 1) { s1 += __shfl_xor(s1, m); s2 += __shfl_xor(s2, m); }
    if (l == 0) { e_sq[k] = s1; qv[k] = s2; c0[k] = s1 - 2.0f * s2 - 1024.0f; }
  } else {
    // ---- LN+GELU: 8 rows/block ----
    const int l = t & 63, w = t >> 6;
    const int r = (blk - 705) * 8 + w;
    const float4 xv = *(const float4*)(x + (size_t)r * 256 + l * 4);
    float s = xv.x + xv.y + xv.z + xv.w;
    for (int m = 32; m; m >>= 1) s += __shfl_xor(s, m);
    const float mu = s * (1.0f / 256.0f);
    float dx = xv.x - mu, dy = xv.y - mu, dz = xv.z - mu, dw = xv.w - mu;
    float vs = dx * dx + dy * dy + dz * dz + dw * dw;
    for (int m = 32; m; m >>= 1) vs += __shfl_xor(vs, m);
    const float rstd = rsqrtf(vs * (1.0f / 256.0f) + 1e-5f);
    float4 gm = *(const float4*)(ln_g + l * 4);
    float4 bt = *(const float4*)(ln_b + l * 4);
    float v0 = dx * rstd * gm.x + bt.x;
    float v1 = dy * rstd * gm.y + bt.y;
    float v2 = dz * rstd * gm.z + bt.z;
    float v3 = dw * rstd * gm.w + bt.w;
    const float is2 = 0.70710678118654752f;
    float4 o;
    o.x = 0.5f * v0 * (1.0f + erff(v0 * is2));
    o.y = 0.5f * v1 * (1.0f + erff(v1 * is2));
    o.z = 0.5f * v2 * (1.0f + erff(v2 * is2));
    o.w = 0.5f * v3 * (1.0f + erff(v3 * is2));
    *(float4*)(g + (size_t)r * 256 + l * 4) = o;
    ushort4 u;
    u.x = f2bf(o.x); u.y = f2bf(o.y); u.z = f2bf(o.z); u.w = f2bf(o.w);
    *(ushort4*)(gbf + (size_t)r * 256 + l * 4) = u;
  }
}

// ---------- G1Z: scores (bn 0..7) + z_sq (bn 8..9). bm on x, BK=64 ----------
// A staged in LDS (swizzled, 2x16KB dbuf); B read DIRECTLY from L2 (panel is
// 256KB, resident) -> half the staging, 4 blocks/CU instead of 2.
__global__ __launch_bounds__(256, 4) void g1_kernel(
    const unsigned short* __restrict__ gbf,     // [32768][256]
    const unsigned short* __restrict__ prowbf,  // [1024][256]
    const unsigned short* __restrict__ qbf,     // [256][256]
    const float* __restrict__ c0, const float* __restrict__ wbv,
    unsigned short* __restrict__ scores,        // [32768][1024]
    float* __restrict__ z_sq) {
  __shared__ unsigned short lds[2][8192];       // A only: [128][64] each
  const int t = threadIdx.x;
  const int bm = blockIdx.x;   // 0..255
  const int bn = blockIdx.y;   // 0..9
  const int m0 = bm * 128;
  const bool is_score = (bn < 8);
  const unsigned short* Bsrc = is_score ? (prowbf + bn * 128 * 256)
                                        : (qbf + (bn - 8) * 128 * 256);
  f32x4 acc[4][4] = {};
  const int w = t >> 6, l = t & 63;
  const int wm = (w >> 1) * 64, wn = (w & 1) * 64;
  const unsigned short* Asrc = gbf + (size_t)m0 * 256;

  auto stageA = [&](int buf, int kt) {
    const int k0 = kt * 64;
#pragma unroll
    for (int i = 0; i < 4; ++i) {
      int ca = t + 256 * i;
      int r = ca >> 3;
      int sp = (ca & 7) ^ (r & 7);
      gload_lds16(Asrc + (size_t)r * 256 + k0 + sp * 8, (char*)&lds[buf][0] + ca * 16);
    }
  };
  stageA(0, 0);
  __syncthreads();
  for (int kt = 0; kt < 4; ++kt) {
    const int cur = kt & 1;
    if (kt < 3) stageA(cur ^ 1, kt + 1);
    const unsigned short* Ab = &lds[cur][0];
#pragma unroll
    for (int ks = 0; ks < 2; ++ks) {
      const int sp = ((ks << 2) + (l >> 4)) ^ (l & 7);
      const int bcol = kt * 64 + ks * 32 + (l >> 4) * 8;
      short8 af[4], bq[4];
#pragma unroll
      for (int ni = 0; ni < 4; ++ni)
        bq[ni] = *(const short8*)(Bsrc + (size_t)(wn + ni * 16 + (l & 15)) * 256 + bcol);
#pragma unroll
      for (int mi = 0; mi < 4; ++mi)
        af[mi] = *(const short8*)(Ab + (wm + mi * 16 + (l & 15)) * 64 + sp * 8);
#pragma unroll
      for (int mi = 0; mi < 4; ++mi)
#pragma unroll
        for (int ni = 0; ni < 4; ++ni)
          acc[mi][ni] = __builtin_amdgcn_mfma_f32_16x16x32_bf16(af[mi], bq[ni], acc[mi][ni], 0, 0, 0);
    }
    __syncthreads();
  }
  const int lrow = (l >> 4) * 4;
  const int lcol = l & 15;
  if (is_score) {
    const int n0 = bn * 128;
#pragma unroll
    for (int mi = 0; mi < 4; ++mi)
#pragma unroll
      for (int ni = 0; ni < 4; ++ni) {
        int gcol = n0 + wn + ni * 16 + lcol;
        float cc = c0[gcol];
#pragma unroll
        for (int r = 0; r < 4; ++r) {
          int grow = m0 + wm + mi * 16 + lrow + r;
          scores[(size_t)grow * 1024 + gcol] = f2bf(cc - 2.0f * acc[mi][ni][r]);
        }
      }
  } else {
    const int d0 = (bn - 8) * 128;
    const float bsq = wbv[256];
#pragma unroll
    for (int mi = 0; mi < 4; ++mi)
#pragma unroll
      for (int r = 0; r < 4; ++r) {
        int grow = m0 + wm + mi * 16 + lrow + r;
        float v = 0.f;
#pragma unroll
        for (int ni = 0; ni < 4; ++ni) {
          int gcol = d0 + wn + ni * 16 + lcol;
          float gv = bf2f(gbf[(size_t)grow * 256 + gcol]);
          v += gv * (acc[mi][ni][r] + wbv[gcol]);
        }
        v += __shfl_xor(v, 1); v += __shfl_xor(v, 2);
        v += __shfl_xor(v, 4); v += __shfl_xor(v, 8);
        if (lcol == 0)
          atomicAdd(&z_sq[grow], v + ((bn == 8 && wn == 0) ? bsq : 0.f));
      }
  }
}

// ---------- min + margin candidates + exact fp32 refine + loss + OUTPUT GATHER ----------
__global__ __launch_bounds__(256) void refine_kernel(
    const unsigned short* __restrict__ scores, const float* __restrict__ g,
    const float* __restrict__ prow, const float* __restrict__ e_sq,
    const float* __restrict__ qv, const float* __restrict__ z_sq,
    const float* __restrict__ eproj, float* __restrict__ out_q,
    float* __restrict__ fidx, float* __restrict__ loss_slots) {
  const int t = threadIdx.x, l = t & 63, w = t >> 6;
  const int r = blockIdx.x * 4 + w;
  const unsigned short* srow = scores + (size_t)r * 1024;
  uint4 q0 = *(const uint4*)(srow + l * 16);
  uint4 q1 = *(const uint4*)(srow + l * 16 + 8);
  float f[16];
  {
    unsigned uu[8] = {q0.x, q0.y, q0.z, q0.w, q1.x, q1.y, q1.z, q1.w};
#pragma unroll
    for (int j = 0; j < 8; ++j) {
      f[2 * j] = __uint_as_float(uu[j] << 16);
      f[2 * j + 1] = __uint_as_float(uu[j] & 0xFFFF0000u);
    }
  }
  float mn = f[0];
#pragma unroll
  for (int j = 1; j < 16; ++j) mn = fminf(mn, f[j]);
  for (int m = 32; m; m >>= 1) mn = fminf(mn, __shfl_xor(mn, m));
  const float T = mn + 8.0f;

  float gv[4];
  const float* gr = g + (size_t)r * 256;
#pragma unroll
  for (int j = 0; j < 4; ++j) gv[j] = gr[l + 64 * j];

  float bestd = 1e30f; int bestk = 0x7fffffff;
#pragma unroll 1
  for (int j = 0; j < 16; ++j) {
    unsigned long long msk = __ballot(f[j] <= T);
    while (msk) {
      int src = __ffsll(msk) - 1;
      msk &= msk - 1;
      int k = src * 16 + j;
      const float* pr = prow + (size_t)k * 256;
      float p = 0.f;
#pragma unroll
      for (int jj = 0; jj < 4; ++jj) p += gv[jj] * pr[l + 64 * jj];
      for (int m = 32; m; m >>= 1) p += __shfl_xor(p, m);
      float d = e_sq[k] - 2.0f * (p + qv[k]);
      if (d < bestd || (d == bestd && k < bestk)) { bestd = d; bestk = k; }
    }
  }
  if (l == 0) {
    fidx[r] = (float)bestk;
    atomicAdd(&loss_slots[r & 2047], z_sq[r] + bestd);
  }
  // gather: quantized[r] = eproj[bestk] (post_b folded in)
  float4 o = *(const float4*)(eproj + (size_t)bestk * 256 + l * 4);
  *(float4*)(out_q + (size_t)r * 256 + l * 4) = o;
}

// ---------- loss finalize ----------
__global__ __launch_bounds__(256) void loss_final_kernel(
    const float* __restrict__ slots, float* __restrict__ out_loss) {
  float s = 0.f;
  for (int i = threadIdx.x; i < 2048; i += 256) s += slots[i];
  for (int m = 32; m; m >>= 1) s += __shfl_xor(s, m);
  __shared__ float ws_[4];
  if ((threadIdx.x & 63) == 0) ws_[threadIdx.x >> 6] = s;
  __syncthreads();
  if (threadIdx.x == 0)
    out_loss[0] = 1.25f * (ws_[0] + ws_[1] + ws_[2] + ws_[3]) / 33554432.0f;
}

extern "C" void kernel_launch(void* const* d_in, const int* in_sizes, int n_in,
                              void* d_out, int out_size, void* d_ws, size_t ws_size,
                              hipStream_t stream) {
  const float* x = (const float*)d_in[0];
  const float* ln_g = (const float*)d_in[1];
  const float* ln_b = (const float*)d_in[2];
  const float* pre_w = (const float*)d_in[3];
  const float* pre_b = (const float*)d_in[4];
  const float* embed = (const float*)d_in[5];
  const float* post_w = (const float*)d_in[6];
  const float* post_b = (const float*)d_in[7];
  float* out_q = (float*)d_out;
  float* out_idx = out_q + 8388608;
  float* out_loss = out_q + 8421376;

  char* ws = (char*)d_ws;
  size_t off = 0;
  auto alloc = [&](size_t n) { char* p = ws + off; off += (n + 255) & ~(size_t)255; return p; };
  float* g_f32 = (float*)alloc(33554432);
  unsigned short* g_bf = (unsigned short*)alloc(16777216);
  unsigned short* scores = (unsigned short*)alloc(67108864);
  float* prow = (float*)alloc(1048576);
  unsigned short* prowbf = (unsigned short*)alloc(524288);
  unsigned short* qbf = (unsigned short*)alloc(131072);
  float* wtf = (float*)alloc(1048576);
  float* eproj = (float*)alloc(1048576);
  float* wbv = (float*)alloc(2048);
  float* e_sq = (float*)alloc(4096);
  float* qv = (float*)alloc(4096);
  float* c0 = (float*)alloc(4096);
  float* z_sq = (float*)alloc(131072);
  float* slots = (float*)alloc(8192);
  (void)ws_size; (void)in_sizes; (void)n_in; (void)out_size;

  prepA_kernel<<<128, 512, 0, stream>>>(pre_w, wtf, z_sq, slots);
  prepB_kernel<<<4801, 512, 0, stream>>>(x, ln_g, ln_b, pre_w, pre_b, embed,
                                         post_w, post_b, wtf, g_f32, g_bf,
                                         prow, prowbf, qbf, wbv, e_sq, qv, c0,
                                         eproj);
  dim3 g1grid(256, 10);
  g1_kernel<<<g1grid, 256, 0, stream>>>(g_bf, prowbf, qbf, c0, wbv, scores, z_sq);
  refine_kernel<<<8192, 256, 0, stream>>>(scores, g_f32, prow, e_sq, qv, z_sq,
                                          eproj, out_q, out_idx, slots);
  loss_final_kernel<<<1, 256, 0, stream>>>(slots, out_loss);
}

// Round 21
// 134.765 us; speedup vs baseline: 1.0778x; 1.0778x over previous
//
#include <hip/hip_runtime.h>
#include <math.h>

// ---------- types / helpers ----------
typedef __attribute__((ext_vector_type(8))) short short8;
typedef __attribute__((ext_vector_type(4))) float f32x4;

__device__ __forceinline__ unsigned short f2bf(float f) {
  unsigned u = __float_as_uint(f);
  unsigned r = (u + 0x7FFFu + ((u >> 16) & 1u)) >> 16;
  return (unsigned short)r;
}

__device__ __forceinline__ float bf2f(unsigned short u) {
  return __uint_as_float((unsigned)u << 16);
}

__device__ __forceinline__ void gload_lds16(const void* gsrc, void* ldst) {
  __builtin_amdgcn_global_load_lds(
      (__attribute__((address_space(1))) void*)(void*)(size_t)(const char*)gsrc,
      (__attribute__((address_space(3))) void*)ldst, 16, 0, 0);
}

// ========== PREP_A: wtrans (0..63) | zero z_sq/slots (64..127) ==========
__global__ __launch_bounds__(512) void prepA_kernel(
    const float* __restrict__ pre_w, float* __restrict__ wtf,
    float* __restrict__ z_sq, float* __restrict__ slots) {
  __shared__ float tile[64][65];
  const int blk = blockIdx.x;
  const int t = threadIdx.x;
  if (blk < 64) {
    const int bc = blk & 15, bd = blk >> 4;
    const int col = t & 63, rr = t >> 6;
#pragma unroll
    for (int i = 0; i < 8; ++i) {
      int row = rr + i * 8;
      tile[row][col] = pre_w[(size_t)(bd * 64 + row) * 1024 + bc * 64 + col];
    }
    __syncthreads();
#pragma unroll
    for (int i = 0; i < 8; ++i) {
      int row = rr + i * 8;
      wtf[(size_t)(bc * 64 + row) * 256 + bd * 64 + col] = tile[col][row];
    }
  } else {
    int i = (blk - 64) * 512 + t;   // 64 blocks * 512 = 32768
    z_sq[i] = 0.f;
    if (i < 2048) slots[i] = 0.f;
  }
}

// ========== PREP_B: pgemm (0..255) | qmat (256..319) | wbv (320) |
//            eproj (321..576) | esq (577..704) | lngelu (705..4800) ==========
// Long-pole small-grid branches FIRST so they overlap the 4096 LN blocks.
__global__ __launch_bounds__(512) void prepB_kernel(
    const float* __restrict__ x, const float* __restrict__ ln_g,
    const float* __restrict__ ln_b, const float* __restrict__ pre_w,
    const float* __restrict__ pre_b, const float* __restrict__ embed,
    const float* __restrict__ post_w, const float* __restrict__ post_b,
    const float* __restrict__ wtf,
    float* __restrict__ g, unsigned short* __restrict__ gbf,
    float* __restrict__ prow, unsigned short* __restrict__ prowbf,
    unsigned short* __restrict__ qbf, float* __restrict__ wbv,
    float* __restrict__ e_sq, float* __restrict__ qv, float* __restrict__ c0,
    float* __restrict__ eproj) {
  __shared__ __align__(16) char smem[49152];
  const int blk = blockIdx.x;
  const int t = threadIdx.x;
  const int sl = t >> 6, jg = t & 63;
  if (blk < 256) {
    // ---- pgemm: P[k][d] = embed[k,:]@wtf[:,d], fp64 accum, 3-round tree ----
    float (*Es)[1024] = (float(*)[1024])smem;             // [4][1024]
    double (*Pd)[1024] = (double(*)[1024])(smem + 16384); // [4][1024]
    const int k0 = blk * 4;
    *(float4*)(&Es[0][0] + t * 8) = *(const float4*)(embed + (size_t)k0 * 1024 + t * 8);
    *(float4*)(&Es[0][0] + t * 8 + 4) = *(const float4*)(embed + (size_t)k0 * 1024 + t * 8 + 4);
    __syncthreads();
    const int cbase = sl * 128;
    double a[4][4] = {};
    const float* wp = wtf + (size_t)cbase * 256 + jg * 4;
#pragma unroll 8
    for (int cc = 0; cc < 128; ++cc) {
      float4 w4 = *(const float4*)(wp + (size_t)cc * 256);
      int c = cbase + cc;
#pragma unroll
      for (int kk = 0; kk < 4; ++kk) {
        double e = (double)Es[kk][c];
        a[kk][0] += (double)w4.x * e;
        a[kk][1] += (double)w4.y * e;
        a[kk][2] += (double)w4.z * e;
        a[kk][3] += (double)w4.w * e;
      }
    }
    if (sl >= 4)
#pragma unroll
      for (int kk = 0; kk < 4; ++kk)
#pragma unroll
        for (int xx = 0; xx < 4; ++xx) Pd[sl - 4][kk * 256 + jg * 4 + xx] = a[kk][xx];
    __syncthreads();
    if (sl < 4)
#pragma unroll
      for (int kk = 0; kk < 4; ++kk)
#pragma unroll
        for (int xx = 0; xx < 4; ++xx) a[kk][xx] += Pd[sl][kk * 256 + jg * 4 + xx];
    __syncthreads();
    if (sl >= 2 && sl < 4)
#pragma unroll
      for (int kk = 0; kk < 4; ++kk)
#pragma unroll
        for (int xx = 0; xx < 4; ++xx) Pd[sl - 2][kk * 256 + jg * 4 + xx] = a[kk][xx];
    __syncthreads();
    if (sl < 2)
#pragma unroll
      for (int kk = 0; kk < 4; ++kk)
#pragma unroll
        for (int xx = 0; xx < 4; ++xx) a[kk][xx] += Pd[sl][kk * 256 + jg * 4 + xx];
    __syncthreads();
    if (sl == 1)
#pragma unroll
      for (int kk = 0; kk < 4; ++kk)
#pragma unroll
        for (int xx = 0; xx < 4; ++xx) Pd[0][kk * 256 + jg * 4 + xx] = a[kk][xx];
    __syncthreads();
    if (sl == 0) {
#pragma unroll
      for (int kk = 0; kk < 4; ++kk) {
        float4 o;
        o.x = (float)(a[kk][0] + Pd[0][kk * 256 + jg * 4 + 0]);
        o.y = (float)(a[kk][1] + Pd[0][kk * 256 + jg * 4 + 1]);
        o.z = (float)(a[kk][2] + Pd[0][kk * 256 + jg * 4 + 2]);
        o.w = (float)(a[kk][3] + Pd[0][kk * 256 + jg * 4 + 3]);
        *(float4*)(prow + (size_t)(k0 + kk) * 256 + jg * 4) = o;
        ushort4 u;
        u.x = f2bf(o.x); u.y = f2bf(o.y); u.z = f2bf(o.z); u.w = f2bf(o.w);
        *(ushort4*)(prowbf + (size_t)(k0 + kk) * 256 + jg * 4) = u;
      }
    }
  } else if (blk < 320) {
    // ---- qmat: Q[a][d] = pre_w[a,:]@wtf[:,d] (bf16) ----
    float (*Es)[1024] = (float(*)[1024])smem;
    float (*Ps)[1024] = (float(*)[1024])(smem + 16384);
    const int a0i = (blk - 256) * 4;
    *(float4*)(&Es[0][0] + t * 8) = *(const float4*)(pre_w + (size_t)a0i * 1024 + t * 8);
    *(float4*)(&Es[0][0] + t * 8 + 4) = *(const float4*)(pre_w + (size_t)a0i * 1024 + t * 8 + 4);
    __syncthreads();
    const int cbase = sl * 128;
    float4 a[4] = {};
    const float* wp = wtf + (size_t)cbase * 256 + jg * 4;
#pragma unroll 8
    for (int cc = 0; cc < 128; ++cc) {
      float4 w4 = *(const float4*)(wp + (size_t)cc * 256);
      int c = cbase + cc;
#pragma unroll
      for (int kk = 0; kk < 4; ++kk) {
        float e = Es[kk][c];
        a[kk].x += w4.x * e; a[kk].y += w4.y * e;
        a[kk].z += w4.z * e; a[kk].w += w4.w * e;
      }
    }
#pragma unroll
    for (int kk = 0; kk < 4; ++kk)
      *(float4*)(&Ps[sl][kk * 256 + jg * 4]) = a[kk];
    __syncthreads();
#pragma unroll
    for (int rep = 0; rep < 2; ++rep) {
      int o = t + rep * 512;
      float s = Ps[0][o] + Ps[1][o] + Ps[2][o] + Ps[3][o] +
                Ps[4][o] + Ps[5][o] + Ps[6][o] + Ps[7][o];
      int kk = o >> 8, j = o & 255;
      qbf[(size_t)(a0i + kk) * 256 + j] = f2bf(s);
    }
  } else if (blk == 320) {
    // ---- wbv = {2*W.b, ||b||^2} ----
    float* Es0 = (float*)smem;
    float (*Ps)[1024] = (float(*)[1024])(smem + 16384);
    const int cbase = sl * 128;
    float4 a = {0.f, 0.f, 0.f, 0.f};
    const float* wp = wtf + (size_t)cbase * 256 + jg * 4;
#pragma unroll 8
    for (int cc = 0; cc < 128; ++cc) {
      float4 w4 = *(const float4*)(wp + (size_t)cc * 256);
      float b = pre_b[cbase + cc];
      a.x += w4.x * b; a.y += w4.y * b; a.z += w4.z * b; a.w += w4.w * b;
    }
    *(float4*)(&Ps[sl][jg * 4]) = a;
    float sb = 0.f;
    if (t < 256) {
      float4 bv = *(const float4*)(pre_b + t * 4);
      sb = bv.x * bv.x + bv.y * bv.y + bv.z * bv.z + bv.w * bv.w;
    }
    for (int m = 32; m; m >>= 1) sb += __shfl_xor(sb, m);
    if ((t & 63) == 0 && t < 256) Es0[t >> 6] = sb;
    __syncthreads();
    if (t < 256) {
      float s = Ps[0][t] + Ps[1][t] + Ps[2][t] + Ps[3][t] +
                Ps[4][t] + Ps[5][t] + Ps[6][t] + Ps[7][t];
      wbv[t] = 2.f * s;
    }
    if (t == 0) wbv[256] = Es0[0] + Es0[1] + Es0[2] + Es0[3];
  } else if (blk < 577) {
    // ---- eproj[k][j] = embed[k,:]@post_w[:,j] + post_b[j] ----
    float (*Es)[1024] = (float(*)[1024])smem;  // [4][1024]
    const int k0 = (blk - 321) * 4;
    *(float4*)(&Es[0][0] + t * 8) = *(const float4*)(embed + (size_t)k0 * 1024 + t * 8);
    *(float4*)(&Es[0][0] + t * 8 + 4) = *(const float4*)(embed + (size_t)k0 * 1024 + t * 8 + 4);
    __syncthreads();
    const int dbase = sl * 128;
    float4 a[4] = {};
    const float* wp = post_w + (size_t)dbase * 256 + jg * 4;
#pragma unroll 8
    for (int dd = 0; dd < 128; ++dd) {
      float4 w4 = *(const float4*)(wp + (size_t)dd * 256);
      int d = dbase + dd;
#pragma unroll
      for (int kk = 0; kk < 4; ++kk) {
        float e = Es[kk][d];
        a[kk].x += w4.x * e; a[kk].y += w4.y * e;
        a[kk].z += w4.z * e; a[kk].w += w4.w * e;
      }
    }
    __syncthreads();               // Es dead; reuse as scratch
    float* scr = (float*)smem;
    if (sl >= 4)
#pragma unroll
      for (int kk = 0; kk < 4; ++kk)
        *(float4*)(scr + (sl - 4) * 1024 + kk * 256 + jg * 4) = a[kk];
    __syncthreads();
    if (sl < 4)
#pragma unroll
      for (int kk = 0; kk < 4; ++kk) {
        float4 v = *(const float4*)(scr + sl * 1024 + kk * 256 + jg * 4);
        a[kk].x += v.x; a[kk].y += v.y; a[kk].z += v.z; a[kk].w += v.w;
      }
    __syncthreads();
    if (sl >= 2 && sl < 4)
#pragma unroll
      for (int kk = 0; kk < 4; ++kk)
        *(float4*)(scr + (sl - 2) * 1024 + kk * 256 + jg * 4) = a[kk];
    __syncthreads();
    if (sl < 2)
#pragma unroll
      for (int kk = 0; kk < 4; ++kk) {
        float4 v = *(const float4*)(scr + sl * 1024 + kk * 256 + jg * 4);
        a[kk].x += v.x; a[kk].y += v.y; a[kk].z += v.z; a[kk].w += v.w;
      }
    __syncthreads();
    if (sl == 1)
#pragma unroll
      for (int kk = 0; kk < 4; ++kk)
        *(float4*)(scr + kk * 256 + jg * 4) = a[kk];
    __syncthreads();
    if (sl == 0) {
      float4 pb = *(const float4*)(post_b + jg * 4);
#pragma unroll
      for (int kk = 0; kk < 4; ++kk) {
        float4 v = *(const float4*)(scr + kk * 256 + jg * 4);
        float4 o;
        o.x = a[kk].x + v.x + pb.x;
        o.y = a[kk].y + v.y + pb.y;
        o.z = a[kk].z + v.z + pb.z;
        o.w = a[kk].w + v.w + pb.w;
        *(float4*)(eproj + (size_t)(k0 + kk) * 256 + jg * 4) = o;
      }
    }
  } else if (blk < 705) {
    // ---- esq: e_sq/qv/c0, 8 k-rows per block ----
    const int l = t & 63, w = t >> 6;
    const int k = (blk - 577) * 8 + w;
    const float* er = embed + (size_t)k * 1024;
    float s1 = 0.f, s2 = 0.f;
#pragma unroll
    for (int j = 0; j < 16; ++j) {
      float e = er[l + 64 * j];
      s1 += e * e;
      s2 += pre_b[l + 64 * j] * e;
    }
    for (int m = 32; m; m >>= 1) { s1 += __shfl_xor(s1, m); s2 += __shfl_xor(s2, m); }
    if (l == 0) { e_sq[k] = s1; qv[k] = s2; c0[k] = s1 - 2.0f * s2 - 1024.0f; }
  } else {
    // ---- LN+GELU: 8 rows/block ----
    const int l = t & 63, w = t >> 6;
    const int r = (blk - 705) * 8 + w;
    const float4 xv = *(const float4*)(x + (size_t)r * 256 + l * 4);
    float s = xv.x + xv.y + xv.z + xv.w;
    for (int m = 32; m; m >>= 1) s += __shfl_xor(s, m);
    const float mu = s * (1.0f / 256.0f);
    float dx = xv.x - mu, dy = xv.y - mu, dz = xv.z - mu, dw = xv.w - mu;
    float vs = dx * dx + dy * dy + dz * dz + dw * dw;
    for (int m = 32; m; m >>= 1) vs += __shfl_xor(vs, m);
    const float rstd = rsqrtf(vs * (1.0f / 256.0f) + 1e-5f);
    float4 gm = *(const float4*)(ln_g + l * 4);
    float4 bt = *(const float4*)(ln_b + l * 4);
    float v0 = dx * rstd * gm.x + bt.x;
    float v1 = dy * rstd * gm.y + bt.y;
    float v2 = dz * rstd * gm.z + bt.z;
    float v3 = dw * rstd * gm.w + bt.w;
    const float is2 = 0.70710678118654752f;
    float4 o;
    o.x = 0.5f * v0 * (1.0f + erff(v0 * is2));
    o.y = 0.5f * v1 * (1.0f + erff(v1 * is2));
    o.z = 0.5f * v2 * (1.0f + erff(v2 * is2));
    o.w = 0.5f * v3 * (1.0f + erff(v3 * is2));
    *(float4*)(g + (size_t)r * 256 + l * 4) = o;
    ushort4 u;
    u.x = f2bf(o.x); u.y = f2bf(o.y); u.z = f2bf(o.z); u.w = f2bf(o.w);
    *(ushort4*)(gbf + (size_t)r * 256 + l * 4) = u;
  }
}

// Swizzled stage: linear LDS dest (gload_lds requirement); global SOURCE slot
// XOR-permuted; read side applies the same XOR. Bank-conflict-free ds_read.
__device__ __forceinline__ void stage_tile256(
    int t, const unsigned short* __restrict__ Asrc, size_t a_row_stride,
    const unsigned short* __restrict__ Bsrc, size_t b_row_stride, int k0,
    unsigned short* Ab, unsigned short* Bb) {
#pragma unroll
  for (int i = 0; i < 4; ++i) {
    int ca = t + 256 * i;
    int r = ca >> 3;
    int sp = (ca & 7) ^ (r & 7);
    gload_lds16(Asrc + (size_t)r * a_row_stride + k0 + sp * 8, (char*)Ab + ca * 16);
    gload_lds16(Bsrc + (size_t)r * b_row_stride + k0 + sp * 8, (char*)Bb + ca * 16);
  }
}

// Proven schedule (round-8, best measured): issue stage(next tile) BEFORE
// compute(cur); one __syncthreads (full drain) per K-step.
#define SAFE_LOOP_BODY(cur)                                                    \
    const unsigned short* Ab = &lds[cur][0];                                   \
    const unsigned short* Bb = &lds[cur][8192];                                \
    _Pragma("unroll")                                                          \
    for (int ks = 0; ks < 2; ++ks) {                                           \
      const int sp = ((ks << 2) + (l >> 4)) ^ (l & 7);                         \
      short8 af[4], bq[4];                                                     \
      _Pragma("unroll")                                                        \
      for (int mi = 0; mi < 4; ++mi)                                           \
        af[mi] = *(const short8*)(Ab + (wm + mi * 16 + (l & 15)) * 64 + sp * 8); \
      _Pragma("unroll")                                                        \
      for (int ni = 0; ni < 4; ++ni)                                           \
        bq[ni] = *(const short8*)(Bb + (wn + ni * 16 + (l & 15)) * 64 + sp * 8); \
      _Pragma("unroll")                                                        \
      for (int mi = 0; mi < 4; ++mi)                                           \
        _Pragma("unroll")                                                      \
        for (int ni = 0; ni < 4; ++ni)                                         \
          acc[mi][ni] = __builtin_amdgcn_mfma_f32_16x16x32_bf16(af[mi], bq[ni], acc[mi][ni], 0, 0, 0); \
    }

// ---------- G1Z: scores (bn 0..7) + z_sq (bn 8..9). bm on x, BK=64 ----------
__global__ __launch_bounds__(256) void g1_kernel(
    const unsigned short* __restrict__ gbf,     // [32768][256]
    const unsigned short* __restrict__ prowbf,  // [1024][256]
    const unsigned short* __restrict__ qbf,     // [256][256]
    const float* __restrict__ c0, const float* __restrict__ wbv,
    unsigned short* __restrict__ scores,        // [32768][1024]
    float* __restrict__ z_sq) {
  __shared__ unsigned short lds[2][16384];
  const int t = threadIdx.x;
  const int bm = blockIdx.x;   // 0..255
  const int bn = blockIdx.y;   // 0..9
  const int m0 = bm * 128;
  const bool is_score = (bn < 8);
  const unsigned short* Bsrc = is_score ? (prowbf + bn * 128 * 256)
                                        : (qbf + (bn - 8) * 128 * 256);
  f32x4 acc[4][4] = {};
  const int w = t >> 6, l = t & 63;
  const int wm = (w >> 1) * 64, wn = (w & 1) * 64;

  stage_tile256(t, gbf + (size_t)m0 * 256, 256, Bsrc, 256, 0, &lds[0][0], &lds[0][8192]);
  __syncthreads();
  for (int kt = 0; kt < 4; ++kt) {
    const int cur = kt & 1;
    if (kt < 3)
      stage_tile256(t, gbf + (size_t)m0 * 256, 256, Bsrc, 256, (kt + 1) * 64,
                    &lds[cur ^ 1][0], &lds[cur ^ 1][8192]);
    SAFE_LOOP_BODY(cur)
    __syncthreads();
  }
  const int lrow = (l >> 4) * 4;
  const int lcol = l & 15;
  if (is_score) {
    const int n0 = bn * 128;
#pragma unroll
    for (int mi = 0; mi < 4; ++mi)
#pragma unroll
      for (int ni = 0; ni < 4; ++ni) {
        int gcol = n0 + wn + ni * 16 + lcol;
        float cc = c0[gcol];
#pragma unroll
        for (int r = 0; r < 4; ++r) {
          int grow = m0 + wm + mi * 16 + lrow + r;
          scores[(size_t)grow * 1024 + gcol] = f2bf(cc - 2.0f * acc[mi][ni][r]);
        }
      }
  } else {
    const int d0 = (bn - 8) * 128;
    const float bsq = wbv[256];
#pragma unroll
    for (int mi = 0; mi < 4; ++mi)
#pragma unroll
      for (int r = 0; r < 4; ++r) {
        int grow = m0 + wm + mi * 16 + lrow + r;
        float v = 0.f;
#pragma unroll
        for (int ni = 0; ni < 4; ++ni) {
          int gcol = d0 + wn + ni * 16 + lcol;
          float gv = bf2f(gbf[(size_t)grow * 256 + gcol]);
          v += gv * (acc[mi][ni][r] + wbv[gcol]);
        }
        v += __shfl_xor(v, 1); v += __shfl_xor(v, 2);
        v += __shfl_xor(v, 4); v += __shfl_xor(v, 8);
        if (lcol == 0)
          atomicAdd(&z_sq[grow], v + ((bn == 8 && wn == 0) ? bsq : 0.f));
      }
  }
}

// ---------- min + margin candidates + exact fp32 refine + loss + OUTPUT GATHER ----------
__global__ __launch_bounds__(256) void refine_kernel(
    const unsigned short* __restrict__ scores, const float* __restrict__ g,
    const float* __restrict__ prow, const float* __restrict__ e_sq,
    const float* __restrict__ qv, const float* __restrict__ z_sq,
    const float* __restrict__ eproj, float* __restrict__ out_q,
    float* __restrict__ fidx, float* __restrict__ loss_slots) {
  const int t = threadIdx.x, l = t & 63, w = t >> 6;
  const int r = blockIdx.x * 4 + w;
  const unsigned short* srow = scores + (size_t)r * 1024;
  uint4 q0 = *(const uint4*)(srow + l * 16);
  uint4 q1 = *(const uint4*)(srow + l * 16 + 8);
  float f[16];
  {
    unsigned uu[8] = {q0.x, q0.y, q0.z, q0.w, q1.x, q1.y, q1.z, q1.w};
#pragma unroll
    for (int j = 0; j < 8; ++j) {
      f[2 * j] = __uint_as_float(uu[j] << 16);
      f[2 * j + 1] = __uint_as_float(uu[j] & 0xFFFF0000u);
    }
  }
  float mn = f[0];
#pragma unroll
  for (int j = 1; j < 16; ++j) mn = fminf(mn, f[j]);
  for (int m = 32; m; m >>= 1) mn = fminf(mn, __shfl_xor(mn, m));
  const float T = mn + 8.0f;

  float gv[4];
  const float* gr = g + (size_t)r * 256;
#pragma unroll
  for (int j = 0; j < 4; ++j) gv[j] = gr[l + 64 * j];

  float bestd = 1e30f; int bestk = 0x7fffffff;
#pragma unroll 1
  for (int j = 0; j < 16; ++j) {
    unsigned long long msk = __ballot(f[j] <= T);
    while (msk) {
      int src = __ffsll(msk) - 1;
      msk &= msk - 1;
      int k = src * 16 + j;
      const float* pr = prow + (size_t)k * 256;
      float p = 0.f;
#pragma unroll
      for (int jj = 0; jj < 4; ++jj) p += gv[jj] * pr[l + 64 * jj];
      for (int m = 32; m; m >>= 1) p += __shfl_xor(p, m);
      float d = e_sq[k] - 2.0f * (p + qv[k]);
      if (d < bestd || (d == bestd && k < bestk)) { bestd = d; bestk = k; }
    }
  }
  if (l == 0) {
    fidx[r] = (float)bestk;
    atomicAdd(&loss_slots[r & 2047], z_sq[r] + bestd);
  }
  // gather: quantized[r] = eproj[bestk] (post_b folded in)
  float4 o = *(const float4*)(eproj + (size_t)bestk * 256 + l * 4);
  *(float4*)(out_q + (size_t)r * 256 + l * 4) = o;
}

// ---------- loss finalize ----------
__global__ __launch_bounds__(256) void loss_final_kernel(
    const float* __restrict__ slots, float* __restrict__ out_loss) {
  float s = 0.f;
  for (int i = threadIdx.x; i < 2048; i += 256) s += slots[i];
  for (int m = 32; m; m >>= 1) s += __shfl_xor(s, m);
  __shared__ float ws_[4];
  if ((threadIdx.x & 63) == 0) ws_[threadIdx.x >> 6] = s;
  __syncthreads();
  if (threadIdx.x == 0)
    out_loss[0] = 1.25f * (ws_[0] + ws_[1] + ws_[2] + ws_[3]) / 33554432.0f;
}

extern "C" void kernel_launch(void* const* d_in, const int* in_sizes, int n_in,
                              void* d_out, int out_size, void* d_ws, size_t ws_size,
                              hipStream_t stream) {
  const float* x = (const float*)d_in[0];
  const float* ln_g = (const float*)d_in[1];
  const float* ln_b = (const float*)d_in[2];
  const float* pre_w = (const float*)d_in[3];
  const float* pre_b = (const float*)d_in[4];
  const float* embed = (const float*)d_in[5];
  const float* post_w = (const float*)d_in[6];
  const float* post_b = (const float*)d_in[7];
  float* out_q = (float*)d_out;
  float* out_idx = out_q + 8388608;
  float* out_loss = out_q + 8421376;

  char* ws = (char*)d_ws;
  size_t off = 0;
  auto alloc = [&](size_t n) { char* p = ws + off; off += (n + 255) & ~(size_t)255; return p; };
  float* g_f32 = (float*)alloc(33554432);
  unsigned short* g_bf = (unsigned short*)alloc(16777216);
  unsigned short* scores = (unsigned short*)alloc(67108864);
  float* prow = (float*)alloc(1048576);
  unsigned short* prowbf = (unsigned short*)alloc(524288);
  unsigned short* qbf = (unsigned short*)alloc(131072);
  float* wtf = (float*)alloc(1048576);
  float* eproj = (float*)alloc(1048576);
  float* wbv = (float*)alloc(2048);
  float* e_sq = (float*)alloc(4096);
  float* qv = (float*)alloc(4096);
  float* c0 = (float*)alloc(4096);
  float* z_sq = (float*)alloc(131072);
  float* slots = (float*)alloc(8192);
  (void)ws_size; (void)in_sizes; (void)n_in; (void)out_size;

  prepA_kernel<<<128, 512, 0, stream>>>(pre_w, wtf, z_sq, slots);
  prepB_kernel<<<4801, 512, 0, stream>>>(x, ln_g, ln_b, pre_w, pre_b, embed,
                                         post_w, post_b, wtf, g_f32, g_bf,
                                         prow, prowbf, qbf, wbv, e_sq, qv, c0,
                                         eproj);
  dim3 g1grid(256, 10);
  g1_kernel<<<g1grid, 256, 0, stream>>>(g_bf, prowbf, qbf, c0, wbv, scores, z_sq);
  refine_kernel<<<8192, 256, 0, stream>>>(scores, g_f32, prow, e_sq, qv, z_sq,
                                          eproj, out_q, out_idx, slots);
  loss_final_kernel<<<1, 256, 0, stream>>>(slots, out_loss);
}

// Round 22
// 134.720 us; speedup vs baseline: 1.0781x; 1.0003x over previous
//
#include <hip/hip_runtime.h>
#include <math.h>

// ---------- types / helpers ----------
typedef __attribute__((ext_vector_type(8))) short short8;
typedef __attribute__((ext_vector_type(4))) float f32x4;

__device__ __forceinline__ unsigned short f2bf(float f) {
  unsigned u = __float_as_uint(f);
  unsigned r = (u + 0x7FFFu + ((u >> 16) & 1u)) >> 16;
  return (unsigned short)r;
}

__device__ __forceinline__ float bf2f(unsigned short u) {
  return __uint_as_float((unsigned)u << 16);
}

__device__ __forceinline__ void gload_lds16(const void* gsrc, void* ldst) {
  __builtin_amdgcn_global_load_lds(
      (__attribute__((address_space(1))) void*)(void*)(size_t)(const char*)gsrc,
      (__attribute__((address_space(3))) void*)ldst, 16, 0, 0);
}

// ========== PREP_A: wtrans (0..63) | zero z_sq/slots (64..127) ==========
__global__ __launch_bounds__(512) void prepA_kernel(
    const float* __restrict__ pre_w, float* __restrict__ wtf,
    float* __restrict__ z_sq, float* __restrict__ slots) {
  __shared__ float tile[64][65];
  const int blk = blockIdx.x;
  const int t = threadIdx.x;
  if (blk < 64) {
    const int bc = blk & 15, bd = blk >> 4;
    const int col = t & 63, rr = t >> 6;
#pragma unroll
    for (int i = 0; i < 8; ++i) {
      int row = rr + i * 8;
      tile[row][col] = pre_w[(size_t)(bd * 64 + row) * 1024 + bc * 64 + col];
    }
    __syncthreads();
#pragma unroll
    for (int i = 0; i < 8; ++i) {
      int row = rr + i * 8;
      wtf[(size_t)(bc * 64 + row) * 256 + bd * 64 + col] = tile[col][row];
    }
  } else {
    int i = (blk - 64) * 512 + t;   // 64 blocks * 512 = 32768
    z_sq[i] = 0.f;
    if (i < 2048) slots[i] = 0.f;
  }
}

// ========== PREP_B: pgemm (0..255) | qmat (256..319) | wbv (320) |
//            eproj (321..576) | esq (577..704) | lngelu (705..4800) ==========
// Long-pole small-grid branches FIRST so they overlap the 4096 LN blocks.
__global__ __launch_bounds__(512) void prepB_kernel(
    const float* __restrict__ x, const float* __restrict__ ln_g,
    const float* __restrict__ ln_b, const float* __restrict__ pre_w,
    const float* __restrict__ pre_b, const float* __restrict__ embed,
    const float* __restrict__ post_w, const float* __restrict__ post_b,
    const float* __restrict__ wtf,
    float* __restrict__ g, unsigned short* __restrict__ gbf,
    float* __restrict__ prow, unsigned short* __restrict__ prowbf,
    unsigned short* __restrict__ qbf, float* __restrict__ wbv,
    float* __restrict__ e_sq, float* __restrict__ qv, float* __restrict__ c0,
    float* __restrict__ eproj) {
  __shared__ __align__(16) char smem[49152];
  const int blk = blockIdx.x;
  const int t = threadIdx.x;
  const int sl = t >> 6, jg = t & 63;
  if (blk < 256) {
    // ---- pgemm: P[k][d] = embed[k,:]@wtf[:,d], fp64 accum, 3-round tree ----
    float (*Es)[1024] = (float(*)[1024])smem;             // [4][1024]
    double (*Pd)[1024] = (double(*)[1024])(smem + 16384); // [4][1024]
    const int k0 = blk * 4;
    *(float4*)(&Es[0][0] + t * 8) = *(const float4*)(embed + (size_t)k0 * 1024 + t * 8);
    *(float4*)(&Es[0][0] + t * 8 + 4) = *(const float4*)(embed + (size_t)k0 * 1024 + t * 8 + 4);
    __syncthreads();
    const int cbase = sl * 128;
    double a[4][4] = {};
    const float* wp = wtf + (size_t)cbase * 256 + jg * 4;
#pragma unroll 8
    for (int cc = 0; cc < 128; ++cc) {
      float4 w4 = *(const float4*)(wp + (size_t)cc * 256);
      int c = cbase + cc;
#pragma unroll
      for (int kk = 0; kk < 4; ++kk) {
        double e = (double)Es[kk][c];
        a[kk][0] += (double)w4.x * e;
        a[kk][1] += (double)w4.y * e;
        a[kk][2] += (double)w4.z * e;
        a[kk][3] += (double)w4.w * e;
      }
    }
    if (sl >= 4)
#pragma unroll
      for (int kk = 0; kk < 4; ++kk)
#pragma unroll
        for (int xx = 0; xx < 4; ++xx) Pd[sl - 4][kk * 256 + jg * 4 + xx] = a[kk][xx];
    __syncthreads();
    if (sl < 4)
#pragma unroll
      for (int kk = 0; kk < 4; ++kk)
#pragma unroll
        for (int xx = 0; xx < 4; ++xx) a[kk][xx] += Pd[sl][kk * 256 + jg * 4 + xx];
    __syncthreads();
    if (sl >= 2 && sl < 4)
#pragma unroll
      for (int kk = 0; kk < 4; ++kk)
#pragma unroll
        for (int xx = 0; xx < 4; ++xx) Pd[sl - 2][kk * 256 + jg * 4 + xx] = a[kk][xx];
    __syncthreads();
    if (sl < 2)
#pragma unroll
      for (int kk = 0; kk < 4; ++kk)
#pragma unroll
        for (int xx = 0; xx < 4; ++xx) a[kk][xx] += Pd[sl][kk * 256 + jg * 4 + xx];
    __syncthreads();
    if (sl == 1)
#pragma unroll
      for (int kk = 0; kk < 4; ++kk)
#pragma unroll
        for (int xx = 0; xx < 4; ++xx) Pd[0][kk * 256 + jg * 4 + xx] = a[kk][xx];
    __syncthreads();
    if (sl == 0) {
#pragma unroll
      for (int kk = 0; kk < 4; ++kk) {
        float4 o;
        o.x = (float)(a[kk][0] + Pd[0][kk * 256 + jg * 4 + 0]);
        o.y = (float)(a[kk][1] + Pd[0][kk * 256 + jg * 4 + 1]);
        o.z = (float)(a[kk][2] + Pd[0][kk * 256 + jg * 4 + 2]);
        o.w = (float)(a[kk][3] + Pd[0][kk * 256 + jg * 4 + 3]);
        *(float4*)(prow + (size_t)(k0 + kk) * 256 + jg * 4) = o;
        ushort4 u;
        u.x = f2bf(o.x); u.y = f2bf(o.y); u.z = f2bf(o.z); u.w = f2bf(o.w);
        *(ushort4*)(prowbf + (size_t)(k0 + kk) * 256 + jg * 4) = u;
      }
    }
  } else if (blk < 320) {
    // ---- qmat: Q[a][d] = pre_w[a,:]@wtf[:,d] (bf16) ----
    float (*Es)[1024] = (float(*)[1024])smem;
    float (*Ps)[1024] = (float(*)[1024])(smem + 16384);
    const int a0i = (blk - 256) * 4;
    *(float4*)(&Es[0][0] + t * 8) = *(const float4*)(pre_w + (size_t)a0i * 1024 + t * 8);
    *(float4*)(&Es[0][0] + t * 8 + 4) = *(const float4*)(pre_w + (size_t)a0i * 1024 + t * 8 + 4);
    __syncthreads();
    const int cbase = sl * 128;
    float4 a[4] = {};
    const float* wp = wtf + (size_t)cbase * 256 + jg * 4;
#pragma unroll 8
    for (int cc = 0; cc < 128; ++cc) {
      float4 w4 = *(const float4*)(wp + (size_t)cc * 256);
      int c = cbase + cc;
#pragma unroll
      for (int kk = 0; kk < 4; ++kk) {
        float e = Es[kk][c];
        a[kk].x += w4.x * e; a[kk].y += w4.y * e;
        a[kk].z += w4.z * e; a[kk].w += w4.w * e;
      }
    }
#pragma unroll
    for (int kk = 0; kk < 4; ++kk)
      *(float4*)(&Ps[sl][kk * 256 + jg * 4]) = a[kk];
    __syncthreads();
#pragma unroll
    for (int rep = 0; rep < 2; ++rep) {
      int o = t + rep * 512;
      float s = Ps[0][o] + Ps[1][o] + Ps[2][o] + Ps[3][o] +
                Ps[4][o] + Ps[5][o] + Ps[6][o] + Ps[7][o];
      int kk = o >> 8, j = o & 255;
      qbf[(size_t)(a0i + kk) * 256 + j] = f2bf(s);
    }
  } else if (blk == 320) {
    // ---- wbv = {2*W.b, ||b||^2} ----
    float* Es0 = (float*)smem;
    float (*Ps)[1024] = (float(*)[1024])(smem + 16384);
    const int cbase = sl * 128;
    float4 a = {0.f, 0.f, 0.f, 0.f};
    const float* wp = wtf + (size_t)cbase * 256 + jg * 4;
#pragma unroll 8
    for (int cc = 0; cc < 128; ++cc) {
      float4 w4 = *(const float4*)(wp + (size_t)cc * 256);
      float b = pre_b[cbase + cc];
      a.x += w4.x * b; a.y += w4.y * b; a.z += w4.z * b; a.w += w4.w * b;
    }
    *(float4*)(&Ps[sl][jg * 4]) = a;
    float sb = 0.f;
    if (t < 256) {
      float4 bv = *(const float4*)(pre_b + t * 4);
      sb = bv.x * bv.x + bv.y * bv.y + bv.z * bv.z + bv.w * bv.w;
    }
    for (int m = 32; m; m >>= 1) sb += __shfl_xor(sb, m);
    if ((t & 63) == 0 && t < 256) Es0[t >> 6] = sb;
    __syncthreads();
    if (t < 256) {
      float s = Ps[0][t] + Ps[1][t] + Ps[2][t] + Ps[3][t] +
                Ps[4][t] + Ps[5][t] + Ps[6][t] + Ps[7][t];
      wbv[t] = 2.f * s;
    }
    if (t == 0) wbv[256] = Es0[0] + Es0[1] + Es0[2] + Es0[3];
  } else if (blk < 577) {
    // ---- eproj[k][j] = embed[k,:]@post_w[:,j] + post_b[j] ----
    float (*Es)[1024] = (float(*)[1024])smem;  // [4][1024]
    const int k0 = (blk - 321) * 4;
    *(float4*)(&Es[0][0] + t * 8) = *(const float4*)(embed + (size_t)k0 * 1024 + t * 8);
    *(float4*)(&Es[0][0] + t * 8 + 4) = *(const float4*)(embed + (size_t)k0 * 1024 + t * 8 + 4);
    __syncthreads();
    const int dbase = sl * 128;
    float4 a[4] = {};
    const float* wp = post_w + (size_t)dbase * 256 + jg * 4;
#pragma unroll 8
    for (int dd = 0; dd < 128; ++dd) {
      float4 w4 = *(const float4*)(wp + (size_t)dd * 256);
      int d = dbase + dd;
#pragma unroll
      for (int kk = 0; kk < 4; ++kk) {
        float e = Es[kk][d];
        a[kk].x += w4.x * e; a[kk].y += w4.y * e;
        a[kk].z += w4.z * e; a[kk].w += w4.w * e;
      }
    }
    __syncthreads();               // Es dead; reuse as scratch
    float* scr = (float*)smem;
    if (sl >= 4)
#pragma unroll
      for (int kk = 0; kk < 4; ++kk)
        *(float4*)(scr + (sl - 4) * 1024 + kk * 256 + jg * 4) = a[kk];
    __syncthreads();
    if (sl < 4)
#pragma unroll
      for (int kk = 0; kk < 4; ++kk) {
        float4 v = *(const float4*)(scr + sl * 1024 + kk * 256 + jg * 4);
        a[kk].x += v.x; a[kk].y += v.y; a[kk].z += v.z; a[kk].w += v.w;
      }
    __syncthreads();
    if (sl >= 2 && sl < 4)
#pragma unroll
      for (int kk = 0; kk < 4; ++kk)
        *(float4*)(scr + (sl - 2) * 1024 + kk * 256 + jg * 4) = a[kk];
    __syncthreads();
    if (sl < 2)
#pragma unroll
      for (int kk = 0; kk < 4; ++kk) {
        float4 v = *(const float4*)(scr + sl * 1024 + kk * 256 + jg * 4);
        a[kk].x += v.x; a[kk].y += v.y; a[kk].z += v.z; a[kk].w += v.w;
      }
    __syncthreads();
    if (sl == 1)
#pragma unroll
      for (int kk = 0; kk < 4; ++kk)
        *(float4*)(scr + kk * 256 + jg * 4) = a[kk];
    __syncthreads();
    if (sl == 0) {
      float4 pb = *(const float4*)(post_b + jg * 4);
#pragma unroll
      for (int kk = 0; kk < 4; ++kk) {
        float4 v = *(const float4*)(scr + kk * 256 + jg * 4);
        float4 o;
        o.x = a[kk].x + v.x + pb.x;
        o.y = a[kk].y + v.y + pb.y;
        o.z = a[kk].z + v.z + pb.z;
        o.w = a[kk].w + v.w + pb.w;
        *(float4*)(eproj + (size_t)(k0 + kk) * 256 + jg * 4) = o;
      }
    }
  } else if (blk < 705) {
    // ---- esq: e_sq/qv/c0, 8 k-rows per block ----
    const int l = t & 63, w = t >> 6;
    const int k = (blk - 577) * 8 + w;
    const float* er = embed + (size_t)k * 1024;
    float s1 = 0.f, s2 = 0.f;
#pragma unroll
    for (int j = 0; j < 16; ++j) {
      float e = er[l + 64 * j];
      s1 += e * e;
      s2 += pre_b[l + 64 * j] * e;
    }
    for (int m = 32; m; m >>= 1) { s1 += __shfl_xor(s1, m); s2 += __shfl_xor(s2, m); }
    if (l == 0) { e_sq[k] = s1; qv[k] = s2; c0[k] = s1 - 2.0f * s2 - 1024.0f; }
  } else {
    // ---- LN+GELU: 8 rows/block ----
    const int l = t & 63, w = t >> 6;
    const int r = (blk - 705) * 8 + w;
    const float4 xv = *(const float4*)(x + (size_t)r * 256 + l * 4);
    float s = xv.x + xv.y + xv.z + xv.w;
    for (int m = 32; m; m >>= 1) s += __shfl_xor(s, m);
    const float mu = s * (1.0f / 256.0f);
    float dx = xv.x - mu, dy = xv.y - mu, dz = xv.z - mu, dw = xv.w - mu;
    float vs = dx * dx + dy * dy + dz * dz + dw * dw;
    for (int m = 32; m; m >>= 1) vs += __shfl_xor(vs, m);
    const float rstd = rsqrtf(vs * (1.0f / 256.0f) + 1e-5f);
    float4 gm = *(const float4*)(ln_g + l * 4);
    float4 bt = *(const float4*)(ln_b + l * 4);
    float v0 = dx * rstd * gm.x + bt.x;
    float v1 = dy * rstd * gm.y + bt.y;
    float v2 = dz * rstd * gm.z + bt.z;
    float v3 = dw * rstd * gm.w + bt.w;
    const float is2 = 0.70710678118654752f;
    float4 o;
    o.x = 0.5f * v0 * (1.0f + erff(v0 * is2));
    o.y = 0.5f * v1 * (1.0f + erff(v1 * is2));
    o.z = 0.5f * v2 * (1.0f + erff(v2 * is2));
    o.w = 0.5f * v3 * (1.0f + erff(v3 * is2));
    *(float4*)(g + (size_t)r * 256 + l * 4) = o;
    ushort4 u;
    u.x = f2bf(o.x); u.y = f2bf(o.y); u.z = f2bf(o.z); u.w = f2bf(o.w);
    *(ushort4*)(gbf + (size_t)r * 256 + l * 4) = u;
  }
}

// Swizzled stage: linear LDS dest (gload_lds requirement); global SOURCE slot
// XOR-permuted; read side applies the same XOR. Bank-conflict-free ds_read.
__device__ __forceinline__ void stage_tile256(
    int t, const unsigned short* __restrict__ Asrc, size_t a_row_stride,
    const unsigned short* __restrict__ Bsrc, size_t b_row_stride, int k0,
    unsigned short* Ab, unsigned short* Bb) {
#pragma unroll
  for (int i = 0; i < 4; ++i) {
    int ca = t + 256 * i;
    int r = ca >> 3;
    int sp = (ca & 7) ^ (r & 7);
    gload_lds16(Asrc + (size_t)r * a_row_stride + k0 + sp * 8, (char*)Ab + ca * 16);
    gload_lds16(Bsrc + (size_t)r * b_row_stride + k0 + sp * 8, (char*)Bb + ca * 16);
  }
}

// Proven schedule (round-8, best measured): issue stage(next tile) BEFORE
// compute(cur); one __syncthreads (full drain) per K-step.
#define SAFE_LOOP_BODY(cur)                                                    \
    const unsigned short* Ab = &lds[cur][0];                                   \
    const unsigned short* Bb = &lds[cur][8192];                                \
    _Pragma("unroll")                                                          \
    for (int ks = 0; ks < 2; ++ks) {                                           \
      const int sp = ((ks << 2) + (l >> 4)) ^ (l & 7);                         \
      short8 af[4], bq[4];                                                     \
      _Pragma("unroll")                                                        \
      for (int mi = 0; mi < 4; ++mi)                                           \
        af[mi] = *(const short8*)(Ab + (wm + mi * 16 + (l & 15)) * 64 + sp * 8); \
      _Pragma("unroll")                                                        \
      for (int ni = 0; ni < 4; ++ni)                                           \
        bq[ni] = *(const short8*)(Bb + (wn + ni * 16 + (l & 15)) * 64 + sp * 8); \
      _Pragma("unroll")                                                        \
      for (int mi = 0; mi < 4; ++mi)                                           \
        _Pragma("unroll")                                                      \
        for (int ni = 0; ni < 4; ++ni)                                         \
          acc[mi][ni] = __builtin_amdgcn_mfma_f32_16x16x32_bf16(af[mi], bq[ni], acc[mi][ni], 0, 0, 0); \
    }

// ---------- G1Z: scores (bn 0..7) + z_sq (bn 8..9). bm on x, BK=64 ----------
__global__ __launch_bounds__(256) void g1_kernel(
    const unsigned short* __restrict__ gbf,     // [32768][256]
    const unsigned short* __restrict__ prowbf,  // [1024][256]
    const unsigned short* __restrict__ qbf,     // [256][256]
    const float* __restrict__ c0, const float* __restrict__ wbv,
    unsigned short* __restrict__ scores,        // [32768][1024]
    float* __restrict__ z_sq) {
  __shared__ unsigned short lds[2][16384];
  const int t = threadIdx.x;
  const int bm = blockIdx.x;   // 0..255
  const int bn = blockIdx.y;   // 0..9
  const int m0 = bm * 128;
  const bool is_score = (bn < 8);
  const unsigned short* Bsrc = is_score ? (prowbf + bn * 128 * 256)
                                        : (qbf + (bn - 8) * 128 * 256);
  f32x4 acc[4][4] = {};
  const int w = t >> 6, l = t & 63;
  const int wm = (w >> 1) * 64, wn = (w & 1) * 64;

  stage_tile256(t, gbf + (size_t)m0 * 256, 256, Bsrc, 256, 0, &lds[0][0], &lds[0][8192]);
  __syncthreads();
  for (int kt = 0; kt < 4; ++kt) {
    const int cur = kt & 1;
    if (kt < 3)
      stage_tile256(t, gbf + (size_t)m0 * 256, 256, Bsrc, 256, (kt + 1) * 64,
                    &lds[cur ^ 1][0], &lds[cur ^ 1][8192]);
    SAFE_LOOP_BODY(cur)
    __syncthreads();
  }
  const int lrow = (l >> 4) * 4;
  const int lcol = l & 15;
  if (is_score) {
    const int n0 = bn * 128;
#pragma unroll
    for (int mi = 0; mi < 4; ++mi)
#pragma unroll
      for (int ni = 0; ni < 4; ++ni) {
        int gcol = n0 + wn + ni * 16 + lcol;
        float cc = c0[gcol];
#pragma unroll
        for (int r = 0; r < 4; ++r) {
          int grow = m0 + wm + mi * 16 + lrow + r;
          scores[(size_t)grow * 1024 + gcol] = f2bf(cc - 2.0f * acc[mi][ni][r]);
        }
      }
  } else {
    const int d0 = (bn - 8) * 128;
    const float bsq = wbv[256];
#pragma unroll
    for (int mi = 0; mi < 4; ++mi)
#pragma unroll
      for (int r = 0; r < 4; ++r) {
        int grow = m0 + wm + mi * 16 + lrow + r;
        float v = 0.f;
#pragma unroll
        for (int ni = 0; ni < 4; ++ni) {
          int gcol = d0 + wn + ni * 16 + lcol;
          float gv = bf2f(gbf[(size_t)grow * 256 + gcol]);
          v += gv * (acc[mi][ni][r] + wbv[gcol]);
        }
        v += __shfl_xor(v, 1); v += __shfl_xor(v, 2);
        v += __shfl_xor(v, 4); v += __shfl_xor(v, 8);
        if (lcol == 0)
          atomicAdd(&z_sq[grow], v + ((bn == 8 && wn == 0) ? bsq : 0.f));
      }
  }
}

// ---------- min + margin candidates + exact fp32 refine + loss + OUTPUT GATHER ----------
__global__ __launch_bounds__(256) void refine_kernel(
    const unsigned short* __restrict__ scores, const float* __restrict__ g,
    const float* __restrict__ prow, const float* __restrict__ e_sq,
    const float* __restrict__ qv, const float* __restrict__ z_sq,
    const float* __restrict__ eproj, float* __restrict__ out_q,
    float* __restrict__ fidx, float* __restrict__ loss_slots) {
  const int t = threadIdx.x, l = t & 63, w = t >> 6;
  const int r = blockIdx.x * 4 + w;
  const unsigned short* srow = scores + (size_t)r * 1024;
  uint4 q0 = *(const uint4*)(srow + l * 16);
  uint4 q1 = *(const uint4*)(srow + l * 16 + 8);
  float f[16];
  {
    unsigned uu[8] = {q0.x, q0.y, q0.z, q0.w, q1.x, q1.y, q1.z, q1.w};
#pragma unroll
    for (int j = 0; j < 8; ++j) {
      f[2 * j] = __uint_as_float(uu[j] << 16);
      f[2 * j + 1] = __uint_as_float(uu[j] & 0xFFFF0000u);
    }
  }
  float mn = f[0];
#pragma unroll
  for (int j = 1; j < 16; ++j) mn = fminf(mn, f[j]);
  for (int m = 32; m; m >>= 1) mn = fminf(mn, __shfl_xor(mn, m));
  const float T = mn + 8.0f;

  float gv[4];
  const float* gr = g + (size_t)r * 256;
#pragma unroll
  for (int j = 0; j < 4; ++j) gv[j] = gr[l + 64 * j];

  float bestd = 1e30f; int bestk = 0x7fffffff;
#pragma unroll 1
  for (int j = 0; j < 16; ++j) {
    unsigned long long msk = __ballot(f[j] <= T);
    while (msk) {
      int src = __ffsll(msk) - 1;
      msk &= msk - 1;
      int k = src * 16 + j;
      const float* pr = prow + (size_t)k * 256;
      float p = 0.f;
#pragma unroll
      for (int jj = 0; jj < 4; ++jj) p += gv[jj] * pr[l + 64 * jj];
      for (int m = 32; m; m >>= 1) p += __shfl_xor(p, m);
      float d = e_sq[k] - 2.0f * (p + qv[k]);
      if (d < bestd || (d == bestd && k < bestk)) { bestd = d; bestk = k; }
    }
  }
  if (l == 0) {
    fidx[r] = (float)bestk;
    atomicAdd(&loss_slots[r & 2047], z_sq[r] + bestd);
  }
  // gather: quantized[r] = eproj[bestk] (post_b folded in)
  float4 o = *(const float4*)(eproj + (size_t)bestk * 256 + l * 4);
  *(float4*)(out_q + (size_t)r * 256 + l * 4) = o;
}

// ---------- loss finalize ----------
__global__ __launch_bounds__(256) void loss_final_kernel(
    const float* __restrict__ slots, float* __restrict__ out_loss) {
  float s = 0.f;
  for (int i = threadIdx.x; i < 2048; i += 256) s += slots[i];
  for (int m = 32; m; m >>= 1) s += __shfl_xor(s, m);
  __shared__ float ws_[4];
  if ((threadIdx.x & 63) == 0) ws_[threadIdx.x >> 6] = s;
  __syncthreads();
  if (threadIdx.x == 0)
    out_loss[0] = 1.25f * (ws_[0] + ws_[1] + ws_[2] + ws_[3]) / 33554432.0f;
}

extern "C" void kernel_launch(void* const* d_in, const int* in_sizes, int n_in,
                              void* d_out, int out_size, void* d_ws, size_t ws_size,
                              hipStream_t stream) {
  const float* x = (const float*)d_in[0];
  const float* ln_g = (const float*)d_in[1];
  const float* ln_b = (const float*)d_in[2];
  const float* pre_w = (const float*)d_in[3];
  const float* pre_b = (const float*)d_in[4];
  const float* embed = (const float*)d_in[5];
  const float* post_w = (const float*)d_in[6];
  const float* post_b = (const float*)d_in[7];
  float* out_q = (float*)d_out;
  float* out_idx = out_q + 8388608;
  float* out_loss = out_q + 8421376;

  char* ws = (char*)d_ws;
  size_t off = 0;
  auto alloc = [&](size_t n) { char* p = ws + off; off += (n + 255) & ~(size_t)255; return p; };
  float* g_f32 = (float*)alloc(33554432);
  unsigned short* g_bf = (unsigned short*)alloc(16777216);
  unsigned short* scores = (unsigned short*)alloc(67108864);
  float* prow = (float*)alloc(1048576);
  unsigned short* prowbf = (unsigned short*)alloc(524288);
  unsigned short* qbf = (unsigned short*)alloc(131072);
  float* wtf = (float*)alloc(1048576);
  float* eproj = (float*)alloc(1048576);
  float* wbv = (float*)alloc(2048);
  float* e_sq = (float*)alloc(4096);
  float* qv = (float*)alloc(4096);
  float* c0 = (float*)alloc(4096);
  float* z_sq = (float*)alloc(131072);
  float* slots = (float*)alloc(8192);
  (void)ws_size; (void)in_sizes; (void)n_in; (void)out_size;

  prepA_kernel<<<128, 512, 0, stream>>>(pre_w, wtf, z_sq, slots);
  prepB_kernel<<<4801, 512, 0, stream>>>(x, ln_g, ln_b, pre_w, pre_b, embed,
                                         post_w, post_b, wtf, g_f32, g_bf,
                                         prow, prowbf, qbf, wbv, e_sq, qv, c0,
                                         eproj);
  dim3 g1grid(256, 10);
  g1_kernel<<<g1grid, 256, 0, stream>>>(g_bf, prowbf, qbf, c0, wbv, scores, z_sq);
  refine_kernel<<<8192, 256, 0, stream>>>(scores, g_f32, prow, e_sq, qv, z_sq,
                                          eproj, out_q, out_idx, slots);
  loss_final_kernel<<<1, 256, 0, stream>>>(slots, out_loss);
}